// Round 1
// baseline (3150.285 us; speedup 1.0000x reference)
//
#include <hip/hip_runtime.h>
#include <hip/hip_bf16.h>
#include <cmath>

#define B_ 4
#define S_ 2048
#define D_ 1024
#define H_ 16
#define DK_ 64
#define FF_ 4096
#define M_ (B_*S_)      // 8192
#define BH_ (B_*H_)     // 64
#define TWOD_ 2048

typedef _Float16 half8 __attribute__((ext_vector_type(8)));
typedef float f32x4 __attribute__((ext_vector_type(4)));

// ---------------- reductions ----------------
__device__ __forceinline__ float block_sum(float v, float* sbuf) {
#pragma unroll
  for (int o = 32; o > 0; o >>= 1) v += __shfl_down(v, o, 64);
  int w = threadIdx.x >> 6;
  if ((threadIdx.x & 63) == 0) sbuf[w] = v;
  __syncthreads();
  float r = sbuf[0] + sbuf[1] + sbuf[2] + sbuf[3];
  __syncthreads();
  return r;
}
__device__ __forceinline__ float block_max(float v, float* sbuf) {
#pragma unroll
  for (int o = 32; o > 0; o >>= 1) v = fmaxf(v, __shfl_down(v, o, 64));
  int w = threadIdx.x >> 6;
  if ((threadIdx.x & 63) == 0) sbuf[w] = v;
  __syncthreads();
  float r = fmaxf(fmaxf(sbuf[0], sbuf[1]), fmaxf(sbuf[2], sbuf[3]));
  __syncthreads();
  return r;
}

// ---------------- weight transpose: W[K][N] f32 -> Wt[N][K] f16 ----------------
__global__ __launch_bounds__(256) void wtrans_kernel(const float* __restrict__ W,
                                                     _Float16* __restrict__ Wt,
                                                     int K, int N) {
  __shared__ float t[32][33];
  int tx = threadIdx.x & 31, ty = threadIdx.x >> 5;  // 32 x 8
  int n0 = blockIdx.x * 32, k0 = blockIdx.y * 32;
#pragma unroll
  for (int j = 0; j < 32; j += 8)
    t[ty + j][tx] = W[(long)(k0 + ty + j) * N + n0 + tx];
  __syncthreads();
#pragma unroll
  for (int j = 0; j < 32; j += 8)
    Wt[(long)(n0 + ty + j) * K + k0 + tx] = (_Float16)t[tx][ty + j];
}

// ---------------- layernorm: f32 [rows][1024] -> f16, optional cwgt ----------------
__global__ __launch_bounds__(256) void ln_kernel(const float* __restrict__ x,
                                                 const float* __restrict__ g,
                                                 const float* __restrict__ bb,
                                                 _Float16* __restrict__ out,
                                                 float* __restrict__ cwgt,
                                                 const float* __restrict__ alphap,
                                                 int doNorm) {
  __shared__ float sbuf[4];
  long row = blockIdx.x;
  const float* xr = x + row * 1024;
  int tid = threadIdx.x;
  float4 v = *(const float4*)(xr + tid * 4);
  float mu = block_sum(v.x + v.y + v.z + v.w, sbuf) * (1.f / 1024.f);
  float dx = v.x - mu, dy = v.y - mu, dz = v.z - mu, dw = v.w - mu;
  float var = block_sum(dx * dx + dy * dy + dz * dz + dw * dw, sbuf) * (1.f / 1024.f);
  float rs = rsqrtf(var + 1e-5f);
  float4 gv = *(const float4*)(g + tid * 4);
  float4 bv = *(const float4*)(bb + tid * 4);
  float y0 = dx * rs * gv.x + bv.x;
  float y1 = dy * rs * gv.y + bv.y;
  float y2 = dz * rs * gv.z + bv.z;
  float y3 = dw * rs * gv.w + bv.w;
  union { ushort4 u; _Float16 h[4]; } o;
  o.h[0] = (_Float16)y0; o.h[1] = (_Float16)y1; o.h[2] = (_Float16)y2; o.h[3] = (_Float16)y3;
  *(ushort4*)(out + row * 1024 + tid * 4) = o.u;
  if (doNorm) {
    float tn = block_sum(y0 * y0 + y1 * y1 + y2 * y2 + y3 * y3, sbuf);
    if (tid == 0) cwgt[row] = expf(-alphap[0] * sqrtf(tn));
  }
}

// ---------------- gauge combine + K reshape to [BH][S][DK] ----------------
__global__ __launch_bounds__(256) void qg_kernel(const _Float16* __restrict__ Q,
                                                 const _Float16* __restrict__ Kk,
                                                 const _Float16* __restrict__ V,
                                                 const float* __restrict__ phase,
                                                 _Float16* __restrict__ Qgh,
                                                 _Float16* __restrict__ Kh) {
  long t = (long)blockIdx.x * 256 + threadIdx.x;  // over BH*S*(DK/4)
  int d = (int)(t & 15) * 4;
  long sm = t >> 4;            // bh*S + s
  int s = (int)(sm & (S_ - 1));
  int bh = (int)(sm >> 11);
  int b = bh >> 4, h = bh & 15;
  float cp = cosf(phase[h]), sp = sinf(phase[h]);
  long src = ((long)(b * S_ + s)) * D_ + h * DK_ + d;
  union { ushort4 u; _Float16 hh[4]; } q, v, k, og;
  q.u = *(const ushort4*)(Q + src);
  v.u = *(const ushort4*)(V + src);
  k.u = *(const ushort4*)(Kk + src);
#pragma unroll
  for (int c = 0; c < 4; c++)
    og.hh[c] = (_Float16)((float)q.hh[c] * cp - (float)v.hh[c] * sp);
  long dst = ((long)bh * S_ + s) * DK_ + d;
  *(ushort4*)(Qgh + dst) = og.u;
  *(ushort4*)(Kh + dst) = k.u;
}

// ---------------- V transpose: [M][D] head-cols -> Vt [BH][DK][S] ----------------
__global__ __launch_bounds__(256) void vtrans_kernel(const _Float16* __restrict__ V,
                                                     _Float16* __restrict__ Vt) {
  int bh = blockIdx.x;
  int b = bh >> 4, h = bh & 15;
  int s0 = blockIdx.y * 64;
  __shared__ _Float16 t[64][65];
  int tid = threadIdx.x;
  int sr = tid >> 4;
  int dc = (tid & 15) * 4;
#pragma unroll
  for (int it = 0; it < 4; it++) {
    int s = it * 16 + sr;
    union { ushort4 u; _Float16 hh[4]; } q;
    q.u = *(const ushort4*)(V + ((long)(b * S_ + s0 + s)) * D_ + h * DK_ + dc);
#pragma unroll
    for (int c = 0; c < 4; c++) t[s][dc + c] = q.hh[c];
  }
  __syncthreads();
  int dr = tid >> 4;
  int sc = (tid & 15) * 4;
#pragma unroll
  for (int it = 0; it < 4; it++) {
    int d = it * 16 + dr;
    union { ushort4 u; _Float16 hh[4]; } o;
#pragma unroll
    for (int c = 0; c < 4; c++) o.hh[c] = t[sc + c][d];
    *(ushort4*)(Vt + ((long)bh * DK_ + d) * S_ + s0 + sc) = o.u;
  }
}

// ---------------- row softmax over [rows][2048] fp32 in place ----------------
__global__ __launch_bounds__(256) void softmax_kernel(float* __restrict__ attn) {
  __shared__ float sbuf[4];
  long row = blockIdx.x;
  float* p = attn + row * (long)S_;
  int tid = threadIdx.x;
  float4 v0 = *(const float4*)(p + tid * 4);
  float4 v1 = *(const float4*)(p + 1024 + tid * 4);
  float m = fmaxf(fmaxf(fmaxf(v0.x, v0.y), fmaxf(v0.z, v0.w)),
                  fmaxf(fmaxf(v1.x, v1.y), fmaxf(v1.z, v1.w)));
  m = block_max(m, sbuf);
  v0.x = expf(v0.x - m); v0.y = expf(v0.y - m); v0.z = expf(v0.z - m); v0.w = expf(v0.w - m);
  v1.x = expf(v1.x - m); v1.y = expf(v1.y - m); v1.z = expf(v1.z - m); v1.w = expf(v1.w - m);
  float s = block_sum(v0.x + v0.y + v0.z + v0.w + v1.x + v1.y + v1.z + v1.w, sbuf);
  float inv = 1.f / s;
  v0.x *= inv; v0.y *= inv; v0.z *= inv; v0.w *= inv;
  v1.x *= inv; v1.y *= inv; v1.z *= inv; v1.w *= inv;
  *(float4*)(p + tid * 4) = v0;
  *(float4*)(p + 1024 + tid * 4) = v1;
}

// ---------------- GEMM: C = A @ Bt^T, 128x128x32 tiles, f16 MFMA ----------------
// MODE 0: f16 out            1: f32 out = acc*scale (scores)
// MODE 2: f16 out = gelu(acc+bias)   3: f32 out = resid + acc
// MODE 4: f32 out = resid + beta*h2 + cwgt[row]*(acc+bias)
// MODE 5: f32 out = resid + acc + bias
template <int MODE, bool AF32>
__global__ __launch_bounds__(256) void gemm_kernel(
    const void* __restrict__ Ap, int lda, long sA,
    const _Float16* __restrict__ Btp, int ldb, long sB,
    void* __restrict__ Cp, int ldc, long sC, int divC, long sC2,
    int Md, int Nd, int Kd,
    const float* __restrict__ bias,
    const float* __restrict__ resid,
    const _Float16* __restrict__ h2p,
    const float* __restrict__ cwgt,
    const float* __restrict__ betap,
    float scale) {
  __shared__ __align__(16) _Float16 As[128 * 40];
  __shared__ __align__(16) _Float16 Bs[128 * 40];
  const int tid = threadIdx.x;
  const int wave = tid >> 6, lane = tid & 63;
  const int wr = wave >> 1, wc = wave & 1;
  const int l15 = lane & 15, quad = lane >> 4;
  const int row0 = blockIdx.y * 128, col0 = blockIdx.x * 128;
  const int bz = blockIdx.z;
  const _Float16* Bt = Btp + (long)bz * sB;

  f32x4 acc[4][4] = {};

  for (int k0 = 0; k0 < Kd; k0 += 32) {
    if constexpr (AF32) {
      const float* A = (const float*)Ap + (long)bz * sA;
#pragma unroll
      for (int p = 0; p < 4; p++) {
        int cid = tid + p * 256;
        int r = cid >> 3, c4 = (cid & 7) << 2;
        int row = row0 + r;
        float4 f = {0.f, 0.f, 0.f, 0.f};
        if (row < Md) f = *(const float4*)(A + (long)row * lda + k0 + c4);
        union { ushort4 u; _Float16 h[4]; } cv;
        cv.h[0] = (_Float16)f.x; cv.h[1] = (_Float16)f.y;
        cv.h[2] = (_Float16)f.z; cv.h[3] = (_Float16)f.w;
        *(ushort4*)&As[r * 40 + c4] = cv.u;
      }
    } else {
      const _Float16* A = (const _Float16*)Ap + (long)bz * sA;
#pragma unroll
      for (int p = 0; p < 2; p++) {
        int cid = tid + p * 256;
        int r = cid >> 2, c8 = (cid & 3) << 3;
        int row = row0 + r;
        uint4 u = {0, 0, 0, 0};
        if (row < Md) u = *(const uint4*)(A + (long)row * lda + k0 + c8);
        *(uint4*)&As[r * 40 + c8] = u;
      }
    }
#pragma unroll
    for (int p = 0; p < 2; p++) {
      int cid = tid + p * 256;
      int r = cid >> 2, c8 = (cid & 3) << 3;
      int rn = col0 + r;
      uint4 u = {0, 0, 0, 0};
      if (rn < Nd) u = *(const uint4*)(Bt + (long)rn * ldb + k0 + c8);
      *(uint4*)&Bs[r * 40 + c8] = u;
    }
    __syncthreads();
    half8 af[4], bfr[4];
#pragma unroll
    for (int i = 0; i < 4; i++)
      af[i] = *(const half8*)&As[(wr * 64 + i * 16 + l15) * 40 + quad * 8];
#pragma unroll
    for (int j = 0; j < 4; j++)
      bfr[j] = *(const half8*)&Bs[(wc * 64 + j * 16 + l15) * 40 + quad * 8];
#pragma unroll
    for (int i = 0; i < 4; i++)
#pragma unroll
      for (int j = 0; j < 4; j++)
        acc[i][j] = __builtin_amdgcn_mfma_f32_16x16x32_f16(af[i], bfr[j], acc[i][j], 0, 0, 0);
    __syncthreads();
  }

  const long coff = (long)(bz / divC) * sC + (long)(bz % divC) * sC2;
  float* C32 = (float*)Cp;
  _Float16* C16 = (_Float16*)Cp;
  float bet = 0.f;
  if constexpr (MODE == 4) bet = betap[0];
#pragma unroll
  for (int i = 0; i < 4; i++) {
    int rbase = row0 + wr * 64 + i * 16 + quad * 4;
#pragma unroll
    for (int j = 0; j < 4; j++) {
      int col = col0 + wc * 64 + j * 16 + l15;
      if (col >= Nd) continue;
#pragma unroll
      for (int r = 0; r < 4; r++) {
        int row = rbase + r;
        if (row >= Md) continue;
        float v = acc[i][j][r];
        long idx = coff + (long)row * ldc + col;
        if constexpr (MODE == 0) {
          C16[idx] = (_Float16)v;
        } else if constexpr (MODE == 1) {
          C32[idx] = v * scale;
        } else if constexpr (MODE == 2) {
          float tv = v + bias[col];
          C16[idx] = (_Float16)(0.5f * tv * (1.f + erff(tv * 0.70710678118654752f)));
        } else if constexpr (MODE == 3) {
          C32[idx] = resid[(long)row * ldc + col] + v;
        } else if constexpr (MODE == 4) {
          C32[idx] = resid[(long)row * ldc + col] + bet * (float)h2p[(long)row * ldc + col] +
                     cwgt[row] * (v + bias[col]);
        } else {
          C32[idx] = resid[(long)row * ldc + col] + v + bias[col];
        }
      }
    }
  }
}

extern "C" void kernel_launch(void* const* d_in, const int* in_sizes, int n_in,
                              void* d_out, int out_size, void* d_ws, size_t ws_size,
                              hipStream_t stream) {
  const float* x   = (const float*)d_in[0];
  const float* wq  = (const float*)d_in[1];
  const float* wk  = (const float*)d_in[2];
  const float* wv  = (const float*)d_in[3];
  const float* wo  = (const float*)d_in[4];
  const float* gph = (const float*)d_in[5];
  const float* cw1 = (const float*)d_in[6];
  const float* cb1 = (const float*)d_in[7];
  const float* cw2 = (const float*)d_in[8];
  const float* cb2 = (const float*)d_in[9];
  const float* alp = (const float*)d_in[10];
  const float* bet = (const float*)d_in[11];
  const float* fw1 = (const float*)d_in[12];
  const float* fb1 = (const float*)d_in[13];
  const float* fw2 = (const float*)d_in[14];
  const float* fb2 = (const float*)d_in[15];
  const float* l1g = (const float*)d_in[16];
  const float* l1b = (const float*)d_in[17];
  const float* l2g = (const float*)d_in[18];
  const float* l2b = (const float*)d_in[19];
  const float* l3g = (const float*)d_in[20];
  const float* l3b = (const float*)d_in[21];

  char* ws = (char*)d_ws;
  const size_t MB = 1ull << 20;
  _Float16* wtq  = (_Float16*)(ws + 0 * MB);
  _Float16* wtk  = (_Float16*)(ws + 2 * MB);
  _Float16* wtv  = (_Float16*)(ws + 4 * MB);
  _Float16* wto  = (_Float16*)(ws + 6 * MB);
  _Float16* wtc1 = (_Float16*)(ws + 8 * MB);
  _Float16* wtc2 = (_Float16*)(ws + 12 * MB);
  _Float16* wtf1 = (_Float16*)(ws + 16 * MB);
  _Float16* wtf2 = (_Float16*)(ws + 24 * MB);
  _Float16* hbuf = (_Float16*)(ws + 32 * MB);   // 16 MB, reused h1/h2/h3
  float*    X1   = (float*)(ws + 48 * MB);      // 32 MB
  float*    X2   = (float*)(ws + 80 * MB);      // 32 MB
  float*    cwgt = (float*)(ws + 112 * MB);     // 32 KB
  char*     AR   = ws + 113 * MB;
  _Float16* Qb   = (_Float16*)(AR + 0 * MB);
  _Float16* Kb   = (_Float16*)(AR + 16 * MB);
  _Float16* Vb   = (_Float16*)(AR + 32 * MB);
  _Float16* Qgh  = (_Float16*)(AR + 48 * MB);
  _Float16* Kh   = (_Float16*)(AR + 64 * MB);
  _Float16* Vt   = (_Float16*)(AR + 80 * MB);
  _Float16* ctx  = (_Float16*)(AR + 96 * MB);
  _Float16* G1   = (_Float16*)(AR + 0 * MB);    // 32 MB, after attention
  _Float16* F1   = (_Float16*)(AR + 0 * MB);    // 64 MB, after conv block

  float* out_x = (float*)d_out;
  float* out_attn = (float*)d_out + (size_t)M_ * D_;

  // weight transposes (f32 [K][N] -> f16 [N][K])
  wtrans_kernel<<<dim3(32, 32), 256, 0, stream>>>(wq, wtq, D_, D_);
  wtrans_kernel<<<dim3(32, 32), 256, 0, stream>>>(wk, wtk, D_, D_);
  wtrans_kernel<<<dim3(32, 32), 256, 0, stream>>>(wv, wtv, D_, D_);
  wtrans_kernel<<<dim3(32, 32), 256, 0, stream>>>(wo, wto, D_, D_);
  wtrans_kernel<<<dim3(64, 32), 256, 0, stream>>>(cw1, wtc1, D_, TWOD_);
  wtrans_kernel<<<dim3(32, 64), 256, 0, stream>>>(cw2, wtc2, TWOD_, D_);
  wtrans_kernel<<<dim3(128, 32), 256, 0, stream>>>(fw1, wtf1, D_, FF_);
  wtrans_kernel<<<dim3(32, 128), 256, 0, stream>>>(fw2, wtf2, FF_, D_);

  // LN1 -> h1
  ln_kernel<<<M_, 256, 0, stream>>>(x, l1g, l1b, hbuf, nullptr, nullptr, 0);

  // Q, K, V = h1 @ w*
  gemm_kernel<0, false><<<dim3(8, 64, 1), 256, 0, stream>>>(
      hbuf, D_, 0, wtq, D_, 0, Qb, D_, 0, 1, 0, M_, D_, D_,
      nullptr, nullptr, nullptr, nullptr, nullptr, 1.f);
  gemm_kernel<0, false><<<dim3(8, 64, 1), 256, 0, stream>>>(
      hbuf, D_, 0, wtk, D_, 0, Kb, D_, 0, 1, 0, M_, D_, D_,
      nullptr, nullptr, nullptr, nullptr, nullptr, 1.f);
  gemm_kernel<0, false><<<dim3(8, 64, 1), 256, 0, stream>>>(
      hbuf, D_, 0, wtv, D_, 0, Vb, D_, 0, 1, 0, M_, D_, D_,
      nullptr, nullptr, nullptr, nullptr, nullptr, 1.f);

  // gauge combine + head-major reshapes
  qg_kernel<<<(BH_ * S_ * (DK_ / 4)) / 256, 256, 0, stream>>>(Qb, Kb, Vb, gph, Qgh, Kh);
  vtrans_kernel<<<dim3(BH_, S_ / 64), 256, 0, stream>>>(Vb, Vt);

  // scores = Qg @ K^T / 8  -> out_attn (raw, fp32)
  gemm_kernel<1, false><<<dim3(16, 16, BH_), 256, 0, stream>>>(
      Qgh, DK_, (long)S_ * DK_, Kh, DK_, (long)S_ * DK_,
      out_attn, S_, (long)S_ * S_, 1, 0, S_, S_, DK_,
      nullptr, nullptr, nullptr, nullptr, nullptr, 0.125f);

  // softmax in place
  softmax_kernel<<<BH_ * S_, 256, 0, stream>>>(out_attn);

  // ctx = P @ V   (A fp32 from d_out, converted in staging)
  gemm_kernel<0, true><<<dim3(1, 16, BH_), 256, 0, stream>>>(
      out_attn, S_, (long)S_ * S_, Vt, S_, (long)DK_ * S_,
      ctx, D_, (long)S_ * D_, H_, DK_, S_, DK_, S_,
      nullptr, nullptr, nullptr, nullptr, nullptr, 1.f);

  // x1 = x + ctx @ wo
  gemm_kernel<3, false><<<dim3(8, 64, 1), 256, 0, stream>>>(
      ctx, D_, 0, wto, D_, 0, X1, D_, 0, 1, 0, M_, D_, D_,
      nullptr, x, nullptr, nullptr, nullptr, 1.f);

  // LN2 -> h2 (+ cwgt)
  ln_kernel<<<M_, 256, 0, stream>>>(X1, l2g, l2b, hbuf, cwgt, alp, 1);

  // g1 = gelu(h2 @ cw1 + cb1)
  gemm_kernel<2, false><<<dim3(16, 64, 1), 256, 0, stream>>>(
      hbuf, D_, 0, wtc1, D_, 0, G1, TWOD_, 0, 1, 0, M_, TWOD_, D_,
      cb1, nullptr, nullptr, nullptr, nullptr, 1.f);

  // x2 = x1 + beta*h2 + cwgt*(g1 @ cw2 + cb2)
  gemm_kernel<4, false><<<dim3(8, 64, 1), 256, 0, stream>>>(
      G1, TWOD_, 0, wtc2, TWOD_, 0, X2, D_, 0, 1, 0, M_, D_, TWOD_,
      cb2, X1, hbuf, cwgt, bet, 1.f);

  // LN3 -> h3
  ln_kernel<<<M_, 256, 0, stream>>>(X2, l3g, l3b, hbuf, nullptr, nullptr, 0);

  // f1 = gelu(h3 @ fw1 + fb1)
  gemm_kernel<2, false><<<dim3(32, 64, 1), 256, 0, stream>>>(
      hbuf, D_, 0, wtf1, D_, 0, F1, FF_, 0, 1, 0, M_, FF_, D_,
      fb1, nullptr, nullptr, nullptr, nullptr, 1.f);

  // out = x2 + f1 @ fw2 + fb2
  gemm_kernel<5, false><<<dim3(8, 64, 1), 256, 0, stream>>>(
      F1, FF_, 0, wtf2, FF_, 0, out_x, D_, 0, 1, 0, M_, D_, FF_,
      fb2, X2, nullptr, nullptr, nullptr, 1.f);
}